// Round 18
// baseline (259.437 us; speedup 1.0000x reference)
//
#include <hip/hip_runtime.h>
#include <stdint.h>

#define NIMG 16
#define HIN 512
#define WIN 512
#define HO 256
#define WO 256
#define HP 258
#define WP 258

typedef unsigned short bf16_t;
typedef unsigned int u32;
typedef short bf16x8 __attribute__((ext_vector_type(8)));
typedef float f32x4 __attribute__((ext_vector_type(4)));
typedef float f32x16 __attribute__((ext_vector_type(16)));

// Channel interleave for fbuf/dbuf: stored position P(c) = 2*(c&31) + (c>>5).
// P^-1(s) = (s&1)*32 + (s>>1). Lets each lane store its (q=0,q=1) co-pair as one u32.

// ---------- bf16 helpers ----------
static __device__ __forceinline__ bf16_t f2bf(float f) {
    u32 u = __float_as_uint(f);
    u += 0x7FFFu + ((u >> 16) & 1u);   // RNE
    return (bf16_t)(u >> 16);
}
static __device__ __forceinline__ float bf_lo(u32 u) { return __uint_as_float(u << 16); }
static __device__ __forceinline__ float bf_hi(u32 u) { return __uint_as_float(u & 0xFFFF0000u); }
static __device__ __forceinline__ u32 pack2(float a, float b) {
    return (u32)f2bf(a) | ((u32)f2bf(b) << 16);
}

// ---------- repack weights (unchanged) ----------
__global__ void repack_w(const float* __restrict__ dec_w, const float* __restrict__ enc_w,
                         bf16_t* __restrict__ wB, bf16_t* __restrict__ wEB) {
    int i = blockIdx.x * 256 + threadIdx.x;
    if (i < 36864) {
        int j  = i & 7;
        int l  = (i >> 3) & 63;
        int q  = (i >> 9) & 1;
        int kc = (i >> 10) & 3;
        int r  = i >> 12;
        int co  = q * 32 + (l & 31);
        int pos = kc * 16 + ((l >> 5) & 1) * 8 + j;
        int ci  = (pos & 1) * 32 + (pos >> 1);
        wB[i] = f2bf(dec_w[(co * 64 + ci) * 9 + r]);
    } else if (i < 36864 + 2048) {
        int t = i - 36864;
        int j = t & 7;
        int l = (t >> 3) & 63;
        int n = (t >> 9) & 1;
        int s = (t >> 10) & 1;
        int co = n * 32 + (l & 31);
        int k  = s * 16 + ((l >> 5) & 1) * 8 + j;
        wEB[t] = (k < 27) ? f2bf(enc_w[co * 27 + k]) : (bf16_t)0;
    }
}

// ---------- zero the 1-px halo (unchanged) ----------
__global__ void zero_halo(bf16_t* __restrict__ buf, int nimg) {
    const int per_img = 1028 * 8;
    int i = blockIdx.x * 256 + threadIdx.x;
    if (i >= nimg * per_img) return;
    int z = i / per_img;
    int rem = i - z * per_img;
    int p = rem >> 3, q = rem & 7;
    int row, col;
    if (p < 258)      { row = 0;           col = p; }
    else if (p < 516) { row = 257;         col = p - 258; }
    else if (p < 772) { row = p - 516 + 1; col = 0; }
    else              { row = p - 772 + 1; col = 257; }
    *(uint4*)(buf + ((size_t)z * HP * WP + (size_t)row * WP + col) * 64 + q * 8) =
        make_uint4(0u, 0u, 0u, 0u);
}

// ---------- encoder (MFMA im2col, unchanged) ----------
__global__ __launch_bounds__(512) void encoder_mfma(
    const float* __restrict__ x, const bf16_t* __restrict__ wEB,
    const float* __restrict__ enc_b, bf16_t* __restrict__ f, int b0)
{
    __shared__ __align__(16) bf16_t xt[3][33][34];

    const int tid = threadIdx.x;
    const int w   = tid >> 6;
    const int l   = tid & 63;
    const int z   = blockIdx.z;
    const int b   = b0 + z;
    const int Y0  = blockIdx.y << 5;
    const int X0  = blockIdx.x << 5;

    const int col = l & 31;
    const float bias0 = enc_b[col];
    const float bias1 = enc_b[32 + col];

    const bf16x8* wv = (const bf16x8*)wEB;
    bf16x8 Bf[2][2];
    #pragma unroll
    for (int s = 0; s < 2; ++s) {
        Bf[s][0] = wv[((s * 2 + 0) << 6) + l];
        Bf[s][1] = wv[((s * 2 + 1) << 6) + l];
    }

    const float* xb = x + (size_t)b * 3 * HIN * WIN;
    for (int i = tid; i < 3267; i += 512) {
        int ci  = i / 1089;
        int rem = i - ci * 1089;
        int yy  = rem / 33, xx = rem - yy * 33;
        int iy = Y0 + yy, ix = X0 + xx;
        float v = (iy < HIN && ix < WIN)
                ? xb[(size_t)ci * HIN * WIN + (size_t)iy * WIN + ix] : 0.f;
        xt[ci][yy][xx] = f2bf(v);
    }
    __syncthreads();

    const int row = l & 31;
    const int py  = 2 * w + (row >> 4);
    const int px  = row & 15;
    const int kh  = (l >> 5) * 8;
    bf16x8 A[2];
    #pragma unroll
    for (int s = 0; s < 2; ++s) {
        #pragma unroll
        for (int j = 0; j < 8; ++j) {
            int k = s * 16 + kh + j;
            k = k < 27 ? k : 26;              // clamp; B=0 kills k>=27
            int ci  = (k * 29) >> 8;
            int tap = k - ci * 9;
            int dy  = (tap * 11) >> 5;
            int dx  = tap - dy * 3;
            A[s][j] = (short)xt[ci][2 * py + dy][2 * px + dx];
        }
    }

    f32x16 acc[2];
    acc[0] = (f32x16){0.f,0.f,0.f,0.f,0.f,0.f,0.f,0.f,0.f,0.f,0.f,0.f,0.f,0.f,0.f,0.f};
    acc[1] = acc[0];
    acc[0] = __builtin_amdgcn_mfma_f32_32x32x16_bf16(A[0], Bf[0][0], acc[0], 0, 0, 0);
    acc[1] = __builtin_amdgcn_mfma_f32_32x32x16_bf16(A[0], Bf[0][1], acc[1], 0, 0, 0);
    acc[0] = __builtin_amdgcn_mfma_f32_32x32x16_bf16(A[1], Bf[1][0], acc[0], 0, 0, 0);
    acc[1] = __builtin_amdgcn_mfma_f32_32x32x16_bf16(A[1], Bf[1][1], acc[1], 0, 0, 0);

    bf16_t* fz = f + (size_t)z * HP * WP * 64;
    const int by = blockIdx.y << 4, bx = blockIdx.x << 4;
    #pragma unroll
    for (int v = 0; v < 16; ++v) {
        const int grow = (v & 3) + 8 * (v >> 2) + 4 * (l >> 5);
        const int flat = w * 32 + grow;
        const int pyy = flat >> 4, pxx = flat & 15;
        float t0 = acc[0][v] + bias0;  t0 = t0 > 0.f ? t0 : 0.f;
        float t1 = acc[1][v] + bias1;  t1 = t1 > 0.f ? t1 : 0.f;
        *(u32*)(fz + ((size_t)(by + pyy + 1) * WP + (bx + pxx + 1)) * 64 + 2 * col) =
            pack2(t0, t1);
    }
}

// ---------- decoder (MFMA 32x32x16): 256 thr = 4 waves, 16x16 tile ----------
// Channel-split schedule: two K-passes of 32 stored-positions each.
//  - LDS tile [324 px][72B] (23.3 KB): padded stride -> 2-way-free banks, no XOR.
//  - T14: pass-1 global reads issued into regs BEFORE pass-0 MFMAs; ds_write after.
// Wave w owns M-frags {2w, 2w+1}. acc[2][2] f32x16 accumulates across both passes.
__global__ __launch_bounds__(256, 4) void decoder_mfma(
    const bf16_t* __restrict__ f, const bf16_t* __restrict__ wB,
    const float* __restrict__ dec_b, bf16_t* __restrict__ d)
{
    __shared__ __align__(16) bf16_t tile[324 * 36];   // 23,328 B

    const int tid = threadIdx.x;
    const int w   = tid >> 6;          // 0..3
    const int l   = tid & 63;
    const int z   = blockIdx.z;
    const int y0  = blockIdx.y << 4, x0 = blockIdx.x << 4;

    const int col = l & 31;
    const float bias0 = dec_b[col];
    const float bias1 = dec_b[32 + col];

    const bf16_t* fbase = f + ((size_t)z * HP * WP + (size_t)y0 * WP + x0) * 64;

    // ---- stage pass 0: stored positions [0,32) of each pixel (64B contiguous) ----
    for (int i = tid; i < 1296; i += 256) {
        int p = i >> 2, qq = i & 3;
        int yy = (p * 456) >> 13, xx = p - yy * 18;   // p/18 exact for p<324
        uint4 v = *(const uint4*)(fbase + ((size_t)yy * WP + xx) * 64 + qq * 8);
        *(uint4*)((char*)tile + p * 72 + qq * 16) = v;
    }

    f32x16 acc[2][2];
    #pragma unroll
    for (int mf = 0; mf < 2; ++mf) {
        acc[mf][0] = (f32x16){0.f,0.f,0.f,0.f,0.f,0.f,0.f,0.f,
                              0.f,0.f,0.f,0.f,0.f,0.f,0.f,0.f};
        acc[mf][1] = acc[mf][0];
    }

    __syncthreads();

    // ---- T14: issue pass-1 global reads now (positions [32,64)); write later ----
    uint4 st[6];
    #pragma unroll
    for (int it = 0; it < 6; ++it) {
        int i = tid + it * 256;
        if (i < 1296) {
            int p = i >> 2, qq = i & 3;
            int yy = (p * 456) >> 13, xx = p - yy * 18;
            st[it] = *(const uint4*)(fbase + ((size_t)yy * WP + xx) * 64 + 32 + qq * 8);
        }
    }

    const bf16x8* wBv = (const bf16x8*)wB;
    const int ty_l = (l >> 4) & 1;
    const int tx_l = l & 15;
    const int kh16 = (l >> 5) << 4;

    // ---- compute pass 0: kc = 0,1 ----
    #pragma unroll
    for (int r = 0; r < 9; ++r) {
        const int dy = r / 3, dx = r - 3 * (r / 3);
        bf16x8 Bf[2][2];
        #pragma unroll
        for (int kcl = 0; kcl < 2; ++kcl) {
            Bf[kcl][0] = wBv[(((r * 4 + kcl) << 1) + 0) * 64 + l];
            Bf[kcl][1] = wBv[(((r * 4 + kcl) << 1) + 1) * 64 + l];
        }
        #pragma unroll
        for (int mf = 0; mf < 2; ++mf) {
            const int p    = (2 * (2 * w + mf) + ty_l + dy) * 18 + tx_l + dx;
            const int base = p * 72 + kh16;
            #pragma unroll
            for (int kcl = 0; kcl < 2; ++kcl) {
                bf16x8 a = *(const bf16x8*)((const char*)tile + base + kcl * 32);
                acc[mf][0] = __builtin_amdgcn_mfma_f32_32x32x16_bf16(a, Bf[kcl][0], acc[mf][0], 0, 0, 0);
                acc[mf][1] = __builtin_amdgcn_mfma_f32_32x32x16_bf16(a, Bf[kcl][1], acc[mf][1], 0, 0, 0);
            }
        }
    }

    __syncthreads();
    // ---- write pass-1 LDS from regs ----
    #pragma unroll
    for (int it = 0; it < 6; ++it) {
        int i = tid + it * 256;
        if (i < 1296) {
            int p = i >> 2, qq = i & 3;
            *(uint4*)((char*)tile + p * 72 + qq * 16) = st[it];
        }
    }
    __syncthreads();

    // ---- compute pass 1: kc = 2,3 ----
    #pragma unroll
    for (int r = 0; r < 9; ++r) {
        const int dy = r / 3, dx = r - 3 * (r / 3);
        bf16x8 Bf[2][2];
        #pragma unroll
        for (int kcl = 0; kcl < 2; ++kcl) {
            Bf[kcl][0] = wBv[(((r * 4 + 2 + kcl) << 1) + 0) * 64 + l];
            Bf[kcl][1] = wBv[(((r * 4 + 2 + kcl) << 1) + 1) * 64 + l];
        }
        #pragma unroll
        for (int mf = 0; mf < 2; ++mf) {
            const int p    = (2 * (2 * w + mf) + ty_l + dy) * 18 + tx_l + dx;
            const int base = p * 72 + kh16;
            #pragma unroll
            for (int kcl = 0; kcl < 2; ++kcl) {
                bf16x8 a = *(const bf16x8*)((const char*)tile + base + kcl * 32);
                acc[mf][0] = __builtin_amdgcn_mfma_f32_32x32x16_bf16(a, Bf[kcl][0], acc[mf][0], 0, 0, 0);
                acc[mf][1] = __builtin_amdgcn_mfma_f32_32x32x16_bf16(a, Bf[kcl][1], acc[mf][1], 0, 0, 0);
            }
        }
    }

    // ---- epilogue: bias+relu -> direct coalesced u32 stores (P-interleaved) ----
    bf16_t* dz = d + (size_t)z * HP * WP * 64;
    #pragma unroll
    for (int mf = 0; mf < 2; ++mf) {
        #pragma unroll
        for (int v = 0; v < 16; ++v) {
            const int grow = (v & 3) + 8 * (v >> 2) + 4 * (l >> 5);
            const int flat = (2 * w + mf) * 32 + grow;    // 0..255
            const int py = flat >> 4, px = flat & 15;
            float t0 = acc[mf][0][v] + bias0;  t0 = t0 > 0.f ? t0 : 0.f;
            float t1 = acc[mf][1][v] + bias1;  t1 = t1 > 0.f ? t1 : 0.f;
            *(u32*)(dz + ((size_t)(y0 + py + 1) * WP + (x0 + px + 1)) * 64 + 2 * col) =
                pack2(t0, t1);
        }
    }
}

// ---------- head: 256 thr, 16x8 px tile, 2 threads/px (q-split) + shfl combine ----------
__global__ __launch_bounds__(256, 6) void head_kernel(
    const bf16_t* __restrict__ d, const float* __restrict__ head_w,
    const float* __restrict__ head_b, const int* __restrict__ cls_id,
    float* __restrict__ out, int b0)
{
    __shared__ __align__(16) bf16_t tile[10 * 18 * 64];   // 23,040 B
    __shared__ float hw[9][64];

    const int tid = threadIdx.x;
    const int z   = blockIdx.z;
    const int b   = b0 + z;
    const int y0  = blockIdx.y << 3;
    const int x0  = blockIdx.x << 4;
    const int cls = cls_id[b];

    // hw indexed by stored position s; true ci = P^-1(s)
    for (int i = tid; i < 576; i += 256) {
        int r = i >> 6, s = i & 63;
        int ci = (s & 1) * 32 + (s >> 1);
        hw[r][s] = head_w[((size_t)cls * 64 + ci) * 9 + r];
    }
    const bf16_t* dbase = d + ((size_t)z * HP * WP + (size_t)y0 * WP + x0) * 64;
    for (int i = tid; i < 1440; i += 256) {
        int p   = i >> 3, q = i & 7;
        int yy  = p / 18, xx = p - yy * 18;
        uint4 v = *(const uint4*)(dbase + ((size_t)yy * WP + xx) * 64 + q * 8);
        int byteoff = (p * 128 + q * 16) ^ ((p & 7) << 4);
        *(uint4*)((char*)tile + byteoff) = v;
    }
    __syncthreads();

    const int half = tid & 1;          // q-half: q = 4*half .. 4*half+3
    const int px   = tid >> 1;         // 0..127
    const int py   = px >> 4, pxx = px & 15;
    float a0 = 0.f, a1 = 0.f, a2 = 0.f, a3 = 0.f;
    #pragma unroll 1
    for (int r = 0; r < 9; ++r) {
        const int dy = r / 3, dx = r - 3 * (r / 3);
        const int p  = (py + dy) * 18 + pxx + dx;
        const int swz = (p & 7) << 4;
        const float* wr = &hw[r][0];
        #pragma unroll
        for (int qi = 0; qi < 4; ++qi) {
            const int q = 4 * half + qi;
            uint4 v = *(const uint4*)((const char*)tile + ((p * 128 + q * 16) ^ swz));
            float4 w0 = *(const float4*)(wr + q * 8);
            float4 w1 = *(const float4*)(wr + q * 8 + 4);
            a0 = fmaf(bf_lo(v.x), w0.x, fmaf(bf_hi(v.x), w0.y, a0));
            a1 = fmaf(bf_lo(v.y), w0.z, fmaf(bf_hi(v.y), w0.w, a1));
            a2 = fmaf(bf_lo(v.z), w1.x, fmaf(bf_hi(v.z), w1.y, a2));
            a3 = fmaf(bf_lo(v.w), w1.z, fmaf(bf_hi(v.w), w1.w, a3));
        }
    }
    float tot = (a0 + a1) + (a2 + a3);
    tot += __shfl_xor(tot, 1);
    if (half == 0) {
        out[(size_t)b * (HO * WO) + (size_t)(y0 + py) * WO + (x0 + pxx)] =
            head_b[cls] + tot;
    }
}

extern "C" void kernel_launch(void* const* d_in, const int* in_sizes, int n_in,
                              void* d_out, int out_size, void* d_ws, size_t ws_size,
                              hipStream_t stream) {
    const float* x      = (const float*)d_in[0];
    const int*   cls_id = (const int*)  d_in[1];
    const float* enc_w  = (const float*)d_in[2];
    const float* enc_b  = (const float*)d_in[3];
    const float* dec_w  = (const float*)d_in[4];
    const float* dec_b  = (const float*)d_in[5];
    const float* head_w = (const float*)d_in[6];
    const float* head_b = (const float*)d_in[7];
    float* out = (float*)d_out;

    const size_t WB_RESERVE = 131072;
    const size_t PER_IMG    = (size_t)HP * WP * 64 * 2;   // 8,519,424 B
    char* ws = (char*)d_ws;
    bf16_t* wB  = (bf16_t*)ws;                 // 73,728 B
    bf16_t* wEB = (bf16_t*)(ws + 81920);       // 4,096 B

    size_t avail = (ws_size > WB_RESERVE) ? (ws_size - WB_RESERVE) : 0;
    int C = (int)(avail / (2 * PER_IMG));
    if (C < 1) C = 1;
    if (C > NIMG) C = NIMG;

    bf16_t* fbuf = (bf16_t*)(ws + WB_RESERVE);
    bf16_t* dbuf = (bf16_t*)(ws + WB_RESERVE + (size_t)C * PER_IMG);

    repack_w<<<dim3(152), 256, 0, stream>>>(dec_w, enc_w, wB, wEB);
    {
        int nthr = C * 1028 * 8;
        int nblk = (nthr + 255) / 256;
        zero_halo<<<dim3(nblk), 256, 0, stream>>>(fbuf, C);
        zero_halo<<<dim3(nblk), 256, 0, stream>>>(dbuf, C);
    }

    int n_rounds = (NIMG + C - 1) / C;
    int per = (NIMG + n_rounds - 1) / n_rounds;
    for (int b0 = 0; b0 < NIMG; b0 += per) {
        const int n = (NIMG - b0 < per) ? (NIMG - b0) : per;
        encoder_mfma<<<dim3(16, 16, n), 512, 0, stream>>>(x, wEB, enc_b, fbuf, b0);
        decoder_mfma<<<dim3(16, 16, n), 256, 0, stream>>>(fbuf, wB, dec_b, dbuf);
        head_kernel <<<dim3(16, 32, n), 256, 0, stream>>>(dbuf, head_w, head_b, cls_id, out, b0);
    }
}

// Round 19
// 224.411 us; speedup vs baseline: 1.1561x; 1.1561x over previous
//
#include <hip/hip_runtime.h>
#include <stdint.h>

#define NIMG 16
#define HIN 512
#define WIN 512
#define HO 256
#define WO 256
#define HP 258
#define WP 258

typedef unsigned short bf16_t;
typedef unsigned int u32;
typedef short bf16x8 __attribute__((ext_vector_type(8)));
typedef float f32x4 __attribute__((ext_vector_type(4)));
typedef float f32x16 __attribute__((ext_vector_type(16)));

// Channel interleave for fbuf/dbuf: stored position P(c) = 2*(c&31) + (c>>5).
// P^-1(s) = (s&1)*32 + (s>>1). Lets each lane store its (q=0,q=1) co-pair as one u32.

// ---------- bf16 helpers ----------
static __device__ __forceinline__ bf16_t f2bf(float f) {
    u32 u = __float_as_uint(f);
    u += 0x7FFFu + ((u >> 16) & 1u);   // RNE
    return (bf16_t)(u >> 16);
}
static __device__ __forceinline__ float bf_lo(u32 u) { return __uint_as_float(u << 16); }
static __device__ __forceinline__ float bf_hi(u32 u) { return __uint_as_float(u & 0xFFFF0000u); }
static __device__ __forceinline__ u32 pack2(float a, float b) {
    return (u32)f2bf(a) | ((u32)f2bf(b) << 16);
}

// async 16B global->LDS: HW writes lane l's data at ldsbase + l*16 (wave-uniform base).
static __device__ __forceinline__ void gload_lds16(const void* g, void* ldsbase) {
    __builtin_amdgcn_global_load_lds(
        (const __attribute__((address_space(1))) void*)g,
        (__attribute__((address_space(3))) void*)ldsbase, 16, 0, 0);
}

// ---------- repack weights (unchanged) ----------
__global__ void repack_w(const float* __restrict__ dec_w, const float* __restrict__ enc_w,
                         bf16_t* __restrict__ wB, bf16_t* __restrict__ wEB) {
    int i = blockIdx.x * 256 + threadIdx.x;
    if (i < 36864) {
        int j  = i & 7;
        int l  = (i >> 3) & 63;
        int q  = (i >> 9) & 1;
        int kc = (i >> 10) & 3;
        int r  = i >> 12;
        int co  = q * 32 + (l & 31);
        int pos = kc * 16 + ((l >> 5) & 1) * 8 + j;
        int ci  = (pos & 1) * 32 + (pos >> 1);
        wB[i] = f2bf(dec_w[(co * 64 + ci) * 9 + r]);
    } else if (i < 36864 + 2048) {
        int t = i - 36864;
        int j = t & 7;
        int l = (t >> 3) & 63;
        int n = (t >> 9) & 1;
        int s = (t >> 10) & 1;
        int co = n * 32 + (l & 31);
        int k  = s * 16 + ((l >> 5) & 1) * 8 + j;
        wEB[t] = (k < 27) ? f2bf(enc_w[co * 27 + k]) : (bf16_t)0;
    }
}

// ---------- zero the 1-px halo (unchanged) ----------
__global__ void zero_halo(bf16_t* __restrict__ buf, int nimg) {
    const int per_img = 1028 * 8;
    int i = blockIdx.x * 256 + threadIdx.x;
    if (i >= nimg * per_img) return;
    int z = i / per_img;
    int rem = i - z * per_img;
    int p = rem >> 3, q = rem & 7;
    int row, col;
    if (p < 258)      { row = 0;           col = p; }
    else if (p < 516) { row = 257;         col = p - 258; }
    else if (p < 772) { row = p - 516 + 1; col = 0; }
    else              { row = p - 772 + 1; col = 257; }
    *(uint4*)(buf + ((size_t)z * HP * WP + (size_t)row * WP + col) * 64 + q * 8) =
        make_uint4(0u, 0u, 0u, 0u);
}

// ---------- encoder (MFMA im2col, unchanged) ----------
__global__ __launch_bounds__(512) void encoder_mfma(
    const float* __restrict__ x, const bf16_t* __restrict__ wEB,
    const float* __restrict__ enc_b, bf16_t* __restrict__ f, int b0)
{
    __shared__ __align__(16) bf16_t xt[3][33][34];

    const int tid = threadIdx.x;
    const int w   = tid >> 6;
    const int l   = tid & 63;
    const int z   = blockIdx.z;
    const int b   = b0 + z;
    const int Y0  = blockIdx.y << 5;
    const int X0  = blockIdx.x << 5;

    const int col = l & 31;
    const float bias0 = enc_b[col];
    const float bias1 = enc_b[32 + col];

    const bf16x8* wv = (const bf16x8*)wEB;
    bf16x8 Bf[2][2];
    #pragma unroll
    for (int s = 0; s < 2; ++s) {
        Bf[s][0] = wv[((s * 2 + 0) << 6) + l];
        Bf[s][1] = wv[((s * 2 + 1) << 6) + l];
    }

    const float* xb = x + (size_t)b * 3 * HIN * WIN;
    for (int i = tid; i < 3267; i += 512) {
        int ci  = i / 1089;
        int rem = i - ci * 1089;
        int yy  = rem / 33, xx = rem - yy * 33;
        int iy = Y0 + yy, ix = X0 + xx;
        float v = (iy < HIN && ix < WIN)
                ? xb[(size_t)ci * HIN * WIN + (size_t)iy * WIN + ix] : 0.f;
        xt[ci][yy][xx] = f2bf(v);
    }
    __syncthreads();

    const int row = l & 31;
    const int py  = 2 * w + (row >> 4);
    const int px  = row & 15;
    const int kh  = (l >> 5) * 8;
    bf16x8 A[2];
    #pragma unroll
    for (int s = 0; s < 2; ++s) {
        #pragma unroll
        for (int j = 0; j < 8; ++j) {
            int k = s * 16 + kh + j;
            k = k < 27 ? k : 26;              // clamp; B=0 kills k>=27
            int ci  = (k * 29) >> 8;
            int tap = k - ci * 9;
            int dy  = (tap * 11) >> 5;
            int dx  = tap - dy * 3;
            A[s][j] = (short)xt[ci][2 * py + dy][2 * px + dx];
        }
    }

    f32x16 acc[2];
    acc[0] = (f32x16){0.f,0.f,0.f,0.f,0.f,0.f,0.f,0.f,0.f,0.f,0.f,0.f,0.f,0.f,0.f,0.f};
    acc[1] = acc[0];
    acc[0] = __builtin_amdgcn_mfma_f32_32x32x16_bf16(A[0], Bf[0][0], acc[0], 0, 0, 0);
    acc[1] = __builtin_amdgcn_mfma_f32_32x32x16_bf16(A[0], Bf[0][1], acc[1], 0, 0, 0);
    acc[0] = __builtin_amdgcn_mfma_f32_32x32x16_bf16(A[1], Bf[1][0], acc[0], 0, 0, 0);
    acc[1] = __builtin_amdgcn_mfma_f32_32x32x16_bf16(A[1], Bf[1][1], acc[1], 0, 0, 0);

    bf16_t* fz = f + (size_t)z * HP * WP * 64;
    const int by = blockIdx.y << 4, bx = blockIdx.x << 4;
    #pragma unroll
    for (int v = 0; v < 16; ++v) {
        const int grow = (v & 3) + 8 * (v >> 2) + 4 * (l >> 5);
        const int flat = w * 32 + grow;
        const int pyy = flat >> 4, pxx = flat & 15;
        float t0 = acc[0][v] + bias0;  t0 = t0 > 0.f ? t0 : 0.f;
        float t1 = acc[1][v] + bias1;  t1 = t1 > 0.f ? t1 : 0.f;
        *(u32*)(fz + ((size_t)(by + pyy + 1) * WP + (bx + pxx + 1)) * 64 + 2 * col) =
            pack2(t0, t1);
    }
}

// ---------- decoder (MFMA 32x32x16): 256 thr = 4 waves, 16x16 tile, 2x B-reuse ----------
// R17 structure + async global_load_lds staging: LDS dest linear (i*16), XOR swizzle
// moved to the per-lane GLOBAL source chunk (qq ^ (p&7)); reads keep the XOR (rule #21).
__global__ __launch_bounds__(256, 4) void decoder_mfma(
    const bf16_t* __restrict__ f, const bf16_t* __restrict__ wB,
    const float* __restrict__ dec_b, bf16_t* __restrict__ d)
{
    __shared__ __align__(16) bf16_t tile[18 * 18 * 64];   // 41,472 B

    const int tid = threadIdx.x;
    const int w   = tid >> 6;          // 0..3
    const int l   = tid & 63;
    const int z   = blockIdx.z;
    const int y0  = blockIdx.y << 4, x0 = blockIdx.x << 4;

    const int col = l & 31;
    const float bias0 = dec_b[col];
    const float bias1 = dec_b[32 + col];

    // ---- async stage 18x18 px f-tile (2592 chunks of 16B) ----
    const bf16_t* fbase = f + ((size_t)z * HP * WP + (size_t)y0 * WP + x0) * 64;
    #pragma unroll
    for (int k = 0; k < 10; ++k) {
        const int ibase = k * 256 + w * 64;        // wave-uniform
        const int i = ibase + l;
        const int p = i >> 3, qq = i & 7;
        const int yy = (p * 57) >> 10;             // p/18, exact for p<324
        const int xx = p - yy * 18;
        const int qr = qq ^ (p & 7);               // pre-swizzled source chunk
        gload_lds16(fbase + ((size_t)yy * WP + xx) * 64 + qr * 8,
                    (char*)tile + (size_t)ibase * 16);
    }
    {   // tail: chunks 2560..2591 (wave 0, lanes < 32)
        const int ibase = 2560 + w * 64;
        const int i = ibase + l;
        if (i < 2592) {
            const int p = i >> 3, qq = i & 7;
            const int yy = (p * 57) >> 10;
            const int xx = p - yy * 18;
            const int qr = qq ^ (p & 7);
            gload_lds16(fbase + ((size_t)yy * WP + xx) * 64 + qr * 8,
                        (char*)tile + (size_t)ibase * 16);
        }
    }

    f32x16 acc[2][2];
    #pragma unroll
    for (int mf = 0; mf < 2; ++mf) {
        acc[mf][0] = (f32x16){0.f,0.f,0.f,0.f,0.f,0.f,0.f,0.f,
                              0.f,0.f,0.f,0.f,0.f,0.f,0.f,0.f};
        acc[mf][1] = acc[mf][0];
    }

    __syncthreads();   // compiler drains vmcnt(0) here

    const bf16x8* wBv = (const bf16x8*)wB;
    const int ty_l = (l >> 4) & 1;
    const int tx_l = l & 15;
    const int kh16 = (l >> 5) << 4;

    #pragma unroll
    for (int r = 0; r < 9; ++r) {
        const int dy = r / 3, dx = r - 3 * (r / 3);
        bf16x8 Bf[4][2];
        #pragma unroll
        for (int kc = 0; kc < 4; ++kc) {
            Bf[kc][0] = wBv[(((r * 4 + kc) << 1) + 0) * 64 + l];
            Bf[kc][1] = wBv[(((r * 4 + kc) << 1) + 1) * 64 + l];
        }
        #pragma unroll
        for (int mf = 0; mf < 2; ++mf) {
            const int p   = (2 * (2 * w + mf) + ty_l + dy) * 18 + tx_l + dx;
            const int swz = (p & 7) << 4;
            const int pb  = p * 128 + kh16;
            #pragma unroll
            for (int kc = 0; kc < 4; ++kc) {
                bf16x8 a = *(const bf16x8*)((const char*)tile + ((pb + kc * 32) ^ swz));
                acc[mf][0] = __builtin_amdgcn_mfma_f32_32x32x16_bf16(a, Bf[kc][0], acc[mf][0], 0, 0, 0);
                acc[mf][1] = __builtin_amdgcn_mfma_f32_32x32x16_bf16(a, Bf[kc][1], acc[mf][1], 0, 0, 0);
            }
        }
    }

    // ---- epilogue: bias+relu -> direct coalesced u32 stores (P-interleaved) ----
    bf16_t* dz = d + (size_t)z * HP * WP * 64;
    #pragma unroll
    for (int mf = 0; mf < 2; ++mf) {
        #pragma unroll
        for (int v = 0; v < 16; ++v) {
            const int grow = (v & 3) + 8 * (v >> 2) + 4 * (l >> 5);
            const int flat = (2 * w + mf) * 32 + grow;    // 0..255
            const int py = flat >> 4, px = flat & 15;
            float t0 = acc[mf][0][v] + bias0;  t0 = t0 > 0.f ? t0 : 0.f;
            float t1 = acc[mf][1][v] + bias1;  t1 = t1 > 0.f ? t1 : 0.f;
            *(u32*)(dz + ((size_t)(y0 + py + 1) * WP + (x0 + px + 1)) * 64 + 2 * col) =
                pack2(t0, t1);
        }
    }
}

// ---------- head: 256 thr, 16x8 px tile, async staging + q-split + shfl combine ----------
__global__ __launch_bounds__(256, 6) void head_kernel(
    const bf16_t* __restrict__ d, const float* __restrict__ head_w,
    const float* __restrict__ head_b, const int* __restrict__ cls_id,
    float* __restrict__ out, int b0)
{
    __shared__ __align__(16) bf16_t tile[10 * 18 * 64];   // 23,040 B
    __shared__ float hw[9][64];

    const int tid = threadIdx.x;
    const int wv  = tid >> 6;
    const int l   = tid & 63;
    const int z   = blockIdx.z;
    const int b   = b0 + z;
    const int y0  = blockIdx.y << 3;
    const int x0  = blockIdx.x << 4;
    const int cls = cls_id[b];

    // ---- async stage 10x18 px d-tile (1440 chunks of 16B) ----
    const bf16_t* dbase = d + ((size_t)z * HP * WP + (size_t)y0 * WP + x0) * 64;
    #pragma unroll
    for (int k = 0; k < 5; ++k) {
        const int ibase = k * 256 + wv * 64;
        const int i = ibase + l;
        const int p = i >> 3, qq = i & 7;
        const int yy = (p * 57) >> 10;            // p/18, exact for p<324
        const int xx = p - yy * 18;
        const int qr = qq ^ (p & 7);
        gload_lds16(dbase + ((size_t)yy * WP + xx) * 64 + qr * 8,
                    (char*)tile + (size_t)ibase * 16);
    }
    {   // tail: chunks 1280..1439 (waves 0,1 full; wave 2 lanes < 32)
        const int ibase = 1280 + wv * 64;
        const int i = ibase + l;
        if (i < 1440) {
            const int p = i >> 3, qq = i & 7;
            const int yy = (p * 57) >> 10;
            const int xx = p - yy * 18;
            const int qr = qq ^ (p & 7);
            gload_lds16(dbase + ((size_t)yy * WP + xx) * 64 + qr * 8,
                        (char*)tile + (size_t)ibase * 16);
        }
    }

    // hw indexed by stored position s; true ci = P^-1(s)
    for (int i = tid; i < 576; i += 256) {
        int r = i >> 6, s = i & 63;
        int ci = (s & 1) * 32 + (s >> 1);
        hw[r][s] = head_w[((size_t)cls * 64 + ci) * 9 + r];
    }
    __syncthreads();

    const int half = tid & 1;          // q-half: q = 4*half .. 4*half+3
    const int px   = tid >> 1;         // 0..127
    const int py   = px >> 4, pxx = px & 15;
    float a0 = 0.f, a1 = 0.f, a2 = 0.f, a3 = 0.f;
    #pragma unroll 1
    for (int r = 0; r < 9; ++r) {
        const int dy = r / 3, dx = r - 3 * (r / 3);
        const int p  = (py + dy) * 18 + pxx + dx;
        const int swz = (p & 7) << 4;
        const float* wr = &hw[r][0];
        #pragma unroll
        for (int qi = 0; qi < 4; ++qi) {
            const int q = 4 * half + qi;
            uint4 v = *(const uint4*)((const char*)tile + ((p * 128 + q * 16) ^ swz));
            float4 w0 = *(const float4*)(wr + q * 8);
            float4 w1 = *(const float4*)(wr + q * 8 + 4);
            a0 = fmaf(bf_lo(v.x), w0.x, fmaf(bf_hi(v.x), w0.y, a0));
            a1 = fmaf(bf_lo(v.y), w0.z, fmaf(bf_hi(v.y), w0.w, a1));
            a2 = fmaf(bf_lo(v.z), w1.x, fmaf(bf_hi(v.z), w1.y, a2));
            a3 = fmaf(bf_lo(v.w), w1.z, fmaf(bf_hi(v.w), w1.w, a3));
        }
    }
    float tot = (a0 + a1) + (a2 + a3);
    tot += __shfl_xor(tot, 1);
    if (half == 0) {
        out[(size_t)b * (HO * WO) + (size_t)(y0 + py) * WO + (x0 + pxx)] =
            head_b[cls] + tot;
    }
}

extern "C" void kernel_launch(void* const* d_in, const int* in_sizes, int n_in,
                              void* d_out, int out_size, void* d_ws, size_t ws_size,
                              hipStream_t stream) {
    const float* x      = (const float*)d_in[0];
    const int*   cls_id = (const int*)  d_in[1];
    const float* enc_w  = (const float*)d_in[2];
    const float* enc_b  = (const float*)d_in[3];
    const float* dec_w  = (const float*)d_in[4];
    const float* dec_b  = (const float*)d_in[5];
    const float* head_w = (const float*)d_in[6];
    const float* head_b = (const float*)d_in[7];
    float* out = (float*)d_out;

    const size_t WB_RESERVE = 131072;
    const size_t PER_IMG    = (size_t)HP * WP * 64 * 2;   // 8,519,424 B
    char* ws = (char*)d_ws;
    bf16_t* wB  = (bf16_t*)ws;                 // 73,728 B
    bf16_t* wEB = (bf16_t*)(ws + 81920);       // 4,096 B

    size_t avail = (ws_size > WB_RESERVE) ? (ws_size - WB_RESERVE) : 0;
    int C = (int)(avail / (2 * PER_IMG));
    if (C < 1) C = 1;
    if (C > NIMG) C = NIMG;

    bf16_t* fbuf = (bf16_t*)(ws + WB_RESERVE);
    bf16_t* dbuf = (bf16_t*)(ws + WB_RESERVE + (size_t)C * PER_IMG);

    repack_w<<<dim3(152), 256, 0, stream>>>(dec_w, enc_w, wB, wEB);
    {
        int nthr = C * 1028 * 8;
        int nblk = (nthr + 255) / 256;
        zero_halo<<<dim3(nblk), 256, 0, stream>>>(fbuf, C);
        zero_halo<<<dim3(nblk), 256, 0, stream>>>(dbuf, C);
    }

    int n_rounds = (NIMG + C - 1) / C;
    int per = (NIMG + n_rounds - 1) / n_rounds;
    for (int b0 = 0; b0 < NIMG; b0 += per) {
        const int n = (NIMG - b0 < per) ? (NIMG - b0) : per;
        encoder_mfma<<<dim3(16, 16, n), 512, 0, stream>>>(x, wEB, enc_b, fbuf, b0);
        decoder_mfma<<<dim3(16, 16, n), 256, 0, stream>>>(fbuf, wB, dec_b, dbuf);
        head_kernel <<<dim3(16, 32, n), 256, 0, stream>>>(dbuf, head_w, head_b, cls_id, out, b0);
    }
}